// Round 11
// baseline (1176.374 us; speedup 1.0000x reference)
//
#include <hip/hip_runtime.h>
#include <hip/hip_fp16.h>

#define N_NODES 100000
#define N_EDGES 1600000
#define F_IN 128
#define HID 64
#define NG 128
#define NC 8        // histogram copies

#define GEMB 1563   // 64-row tiles: ceil(100000/64)
#define DEGB4 1563  // hist blocks, 4 edges/thread: ceil(1.6M/1024)
#define CNTB 391    // ceil(100K/256)
#define NB   391    // scan blocks over nodes

// 16 fp32 FMAs: acc(4 cols) += xv(4 k-vals) * w0..w3 (rows of W chunk)
#define FMA_ROW(acc, xv) \
    acc.x = fmaf(xv.x, w0.x, acc.x); acc.y = fmaf(xv.x, w0.y, acc.y); \
    acc.z = fmaf(xv.x, w0.z, acc.z); acc.w = fmaf(xv.x, w0.w, acc.w); \
    acc.x = fmaf(xv.y, w1.x, acc.x); acc.y = fmaf(xv.y, w1.y, acc.y); \
    acc.z = fmaf(xv.y, w1.z, acc.z); acc.w = fmaf(xv.y, w1.w, acc.w); \
    acc.x = fmaf(xv.z, w2.x, acc.x); acc.y = fmaf(xv.z, w2.y, acc.y); \
    acc.z = fmaf(xv.z, w2.z, acc.z); acc.w = fmaf(xv.z, w2.w, acc.w); \
    acc.x = fmaf(xv.w, w3.x, acc.x); acc.y = fmaf(xv.w, w3.y, acc.y); \
    acc.z = fmaf(xv.w, w3.z, acc.z); acc.w = fmaf(xv.w, w3.w, acc.w);

#define FMA_EDGE(hh, ww) \
    acc.x = fmaf(hh.x, ww, acc.x); acc.y = fmaf(hh.y, ww, acc.y); \
    acc.z = fmaf(hh.z, ww, acc.z); acc.w = fmaf(hh.w, ww, acc.w);

#define ADD_EDGE(hh) \
    acc.x += hh.x; acc.y += hh.y; acc.z += hh.z; acc.w += hh.w;

// ---- fp16x4 load/store helpers (8B) ----
__device__ __forceinline__ float4 ldh4(const __half* p) {
    uint2 u = *(const uint2*)p;
    __half2 a = *(__half2*)&u.x, b = *(__half2*)&u.y;
    float2 fa = __half22float2(a), fb = __half22float2(b);
    return make_float4(fa.x, fa.y, fb.x, fb.y);
}
__device__ __forceinline__ void sth4(__half* p, float4 v) {
    __half2 a = __floats2half2_rn(v.x, v.y), b = __floats2half2_rn(v.z, v.w);
    uint2 u; u.x = *(unsigned int*)&a; u.y = *(unsigned int*)&b;
    *(uint2*)p = u;
}

// ---- edge-sum, layer1 (weighted): sum_e dinv[s]*h16[s][c4..c4+3] ----
__device__ __forceinline__ float4 gather_row_w(const __half* __restrict__ h16,
                                               const int* __restrict__ eidx,
                                               const float* __restrict__ dinv,
                                               int e0, int e1, int c4) {
    float4 acc = make_float4(0.f, 0.f, 0.f, 0.f);
    int e = e0;
    for (; e + 7 < e1; e += 8) {
        int s0 = eidx[e],     s1 = eidx[e + 1], s2 = eidx[e + 2], s3 = eidx[e + 3];
        int s4 = eidx[e + 4], s5 = eidx[e + 5], s6 = eidx[e + 6], s7 = eidx[e + 7];
        float w0 = dinv[s0], w1 = dinv[s1], w2 = dinv[s2], w3 = dinv[s3];
        float w4 = dinv[s4], w5 = dinv[s5], w6 = dinv[s6], w7 = dinv[s7];
        float4 h0 = ldh4(&h16[(size_t)s0 * HID + c4]);
        float4 h1 = ldh4(&h16[(size_t)s1 * HID + c4]);
        float4 h2 = ldh4(&h16[(size_t)s2 * HID + c4]);
        float4 h3 = ldh4(&h16[(size_t)s3 * HID + c4]);
        float4 h4 = ldh4(&h16[(size_t)s4 * HID + c4]);
        float4 h5 = ldh4(&h16[(size_t)s5 * HID + c4]);
        float4 h6 = ldh4(&h16[(size_t)s6 * HID + c4]);
        float4 h7 = ldh4(&h16[(size_t)s7 * HID + c4]);
        FMA_EDGE(h0, w0); FMA_EDGE(h1, w1); FMA_EDGE(h2, w2); FMA_EDGE(h3, w3);
        FMA_EDGE(h4, w4); FMA_EDGE(h5, w5); FMA_EDGE(h6, w6); FMA_EDGE(h7, w7);
    }
    if (e + 3 < e1) {
        int s0 = eidx[e], s1 = eidx[e + 1], s2 = eidx[e + 2], s3 = eidx[e + 3];
        float w0 = dinv[s0], w1 = dinv[s1], w2 = dinv[s2], w3 = dinv[s3];
        float4 h0 = ldh4(&h16[(size_t)s0 * HID + c4]);
        float4 h1 = ldh4(&h16[(size_t)s1 * HID + c4]);
        float4 h2 = ldh4(&h16[(size_t)s2 * HID + c4]);
        float4 h3 = ldh4(&h16[(size_t)s3 * HID + c4]);
        FMA_EDGE(h0, w0); FMA_EDGE(h1, w1); FMA_EDGE(h2, w2); FMA_EDGE(h3, w3);
        e += 4;
    }
    for (; e < e1; ++e) {
        int s0 = eidx[e];
        float w0 = dinv[s0];
        float4 h0 = ldh4(&h16[(size_t)s0 * HID + c4]);
        FMA_EDGE(h0, w0);
    }
    return acc;
}

// ---- edge-sum, layer2 (pre-scaled rows): sum_e hw16[s][c4..c4+3] ----
__device__ __forceinline__ float4 gather_row_nw(const __half* __restrict__ h16,
                                                const int* __restrict__ eidx,
                                                int e0, int e1, int c4) {
    float4 acc = make_float4(0.f, 0.f, 0.f, 0.f);
    int e = e0;
    for (; e + 7 < e1; e += 8) {
        int s0 = eidx[e],     s1 = eidx[e + 1], s2 = eidx[e + 2], s3 = eidx[e + 3];
        int s4 = eidx[e + 4], s5 = eidx[e + 5], s6 = eidx[e + 6], s7 = eidx[e + 7];
        float4 h0 = ldh4(&h16[(size_t)s0 * HID + c4]);
        float4 h1 = ldh4(&h16[(size_t)s1 * HID + c4]);
        float4 h2 = ldh4(&h16[(size_t)s2 * HID + c4]);
        float4 h3 = ldh4(&h16[(size_t)s3 * HID + c4]);
        float4 h4 = ldh4(&h16[(size_t)s4 * HID + c4]);
        float4 h5 = ldh4(&h16[(size_t)s5 * HID + c4]);
        float4 h6 = ldh4(&h16[(size_t)s6 * HID + c4]);
        float4 h7 = ldh4(&h16[(size_t)s7 * HID + c4]);
        ADD_EDGE(h0); ADD_EDGE(h1); ADD_EDGE(h2); ADD_EDGE(h3);
        ADD_EDGE(h4); ADD_EDGE(h5); ADD_EDGE(h6); ADD_EDGE(h7);
    }
    if (e + 3 < e1) {
        int s0 = eidx[e], s1 = eidx[e + 1], s2 = eidx[e + 2], s3 = eidx[e + 3];
        float4 h0 = ldh4(&h16[(size_t)s0 * HID + c4]);
        float4 h1 = ldh4(&h16[(size_t)s1 * HID + c4]);
        float4 h2 = ldh4(&h16[(size_t)s2 * HID + c4]);
        float4 h3 = ldh4(&h16[(size_t)s3 * HID + c4]);
        ADD_EDGE(h0); ADD_EDGE(h1); ADD_EDGE(h2); ADD_EDGE(h3);
        e += 4;
    }
    for (; e < e1; ++e) {
        int s0 = eidx[e];
        float4 h0 = ldh4(&h16[(size_t)s0 * HID + c4]);
        ADD_EDGE(h0);
    }
    return acc;
}

// ---- 64x64 GEMM tile -> fp16 out; 2-row sub-batches to fit 64 VGPR ----
template <int K>
__device__ __forceinline__ void gemm_tile(const float* __restrict__ X,
                                          const float* __restrict__ W,
                                          __half* __restrict__ H16,
                                          int tile, float* smem) {
    const int tid = threadIdx.x;
    const int rg  = tid >> 4;
    const int c4  = (tid & 15) * 4;
    const int r0  = tile * 64 + rg * 4;
    const bool full = (r0 + 3 < N_NODES);

    float4 a0 = {0,0,0,0}, a1 = {0,0,0,0}, a2 = {0,0,0,0}, a3 = {0,0,0,0};

    for (int kh = 0; kh < K; kh += 64) {
        __syncthreads();
        for (int i = tid; i < 1024; i += 256)
            ((float4*)smem)[i] = ((const float4*)(W + kh * 64))[i];
        __syncthreads();

        const float* Xb = X + (size_t)r0 * K + kh;
        #pragma unroll 4
        for (int k2 = 0; k2 < 64; k2 += 4) {
            float4 w0 = *(float4*)&smem[(k2 + 0) * 64 + c4];
            float4 w1 = *(float4*)&smem[(k2 + 1) * 64 + c4];
            float4 w2 = *(float4*)&smem[(k2 + 2) * 64 + c4];
            float4 w3 = *(float4*)&smem[(k2 + 3) * 64 + c4];
            {   // rows 0,1
                float4 x0 = {0,0,0,0}, x1 = {0,0,0,0};
                if (full) {
                    x0 = *(const float4*)&Xb[0 * (size_t)K + k2];
                    x1 = *(const float4*)&Xb[1 * (size_t)K + k2];
                } else {
                    if (r0 + 0 < N_NODES) x0 = *(const float4*)&Xb[0 * (size_t)K + k2];
                    if (r0 + 1 < N_NODES) x1 = *(const float4*)&Xb[1 * (size_t)K + k2];
                }
                FMA_ROW(a0, x0);
                FMA_ROW(a1, x1);
            }
            {   // rows 2,3
                float4 x2 = {0,0,0,0}, x3 = {0,0,0,0};
                if (full) {
                    x2 = *(const float4*)&Xb[2 * (size_t)K + k2];
                    x3 = *(const float4*)&Xb[3 * (size_t)K + k2];
                } else {
                    if (r0 + 2 < N_NODES) x2 = *(const float4*)&Xb[2 * (size_t)K + k2];
                    if (r0 + 3 < N_NODES) x3 = *(const float4*)&Xb[3 * (size_t)K + k2];
                }
                FMA_ROW(a2, x2);
                FMA_ROW(a3, x3);
            }
        }
    }

    if (full) {
        sth4(&H16[(size_t)(r0 + 0) * HID + c4], a0);
        sth4(&H16[(size_t)(r0 + 1) * HID + c4], a1);
        sth4(&H16[(size_t)(r0 + 2) * HID + c4], a2);
        sth4(&H16[(size_t)(r0 + 3) * HID + c4], a3);
    } else {
        if (r0 + 0 < N_NODES) sth4(&H16[(size_t)(r0 + 0) * HID + c4], a0);
        if (r0 + 1 < N_NODES) sth4(&H16[(size_t)(r0 + 1) * HID + c4], a1);
        if (r0 + 2 < N_NODES) sth4(&H16[(size_t)(r0 + 2) * HID + c4], a2);
        if (r0 + 3 < N_NODES) sth4(&H16[(size_t)(r0 + 3) * HID + c4], a3);
    }
}

// ---- fused front: [gemm1 | ILP-4 NC-way deg histogram + rank | counts] ----
// launch_bounds(256,8): cap VGPR at 64 so hist phase runs 8 blocks/CU
__global__ __launch_bounds__(256, 8) void k_front(const int* __restrict__ dst,
                                                  int* __restrict__ deg8,   // [NC][N]
                                                  int* __restrict__ rank,
                                                  const int* __restrict__ batch,
                                                  int* __restrict__ gcnt,
                                                  const float* __restrict__ X,
                                                  const float* __restrict__ W,
                                                  __half* __restrict__ H16) {
    __shared__ float smem[4096];   // 16 KB: gemm W-stage / count bins
    int bid = blockIdx.x;
    if (bid < GEMB) {
        gemm_tile<F_IN>(X, W, H16, bid, smem);
    } else if (bid < GEMB + DEGB4) {
        int hb = bid - GEMB;
        int base = (hb * 256 + threadIdx.x) * 4;
        int c = hb & (NC - 1);            // edge e -> copy (e>>10)&7
        if (base < N_EDGES) {             // N_EDGES % 4 == 0 -> full int4 ok
            int4 d4 = *(const int4*)&dst[base];
            int* dg = deg8 + (size_t)c * N_NODES;
            int r0 = atomicAdd(&dg[d4.x], 1);
            int r1 = atomicAdd(&dg[d4.y], 1);
            int r2 = atomicAdd(&dg[d4.z], 1);
            int r3 = atomicAdd(&dg[d4.w], 1);
            *(int4*)&rank[base] = make_int4(r0, r1, r2, r3);
        }
    } else {
        int* bins = (int*)smem;
        if (threadIdx.x < NG) bins[threadIdx.x] = 0;
        __syncthreads();
        int i = (bid - GEMB - DEGB4) * 256 + threadIdx.x;
        if (i < N_NODES) atomicAdd(&bins[batch[i]], 1);
        __syncthreads();
        if (threadIdx.x < NG && bins[threadIdx.x] != 0)
            atomicAdd(&gcnt[threadIdx.x], bins[threadIdx.x]);
    }
}

// ---------------- scan step 1: per-block sums of total deg ----------------
__global__ __launch_bounds__(256) void k_blocksum(const int* __restrict__ deg8,
                                                  int* __restrict__ bsum) {
    __shared__ int red[256];
    int i = blockIdx.x * 256 + threadIdx.x;
    int v = 0;
    if (i < N_NODES) {
        #pragma unroll
        for (int c = 0; c < NC; ++c) v += deg8[(size_t)c * N_NODES + i];
    }
    red[threadIdx.x] = v;
    __syncthreads();
    for (int off = 128; off > 0; off >>= 1) {
        if (threadIdx.x < off) red[threadIdx.x] += red[threadIdx.x + off];
        __syncthreads();
    }
    if (threadIdx.x == 0) bsum[blockIdx.x] = red[0];
}

// ---------------- scan step 2: exclusive scan of block sums ----------------
__global__ __launch_bounds__(512) void k_scanb(const int* __restrict__ bsum,
                                               int* __restrict__ boff, int nb) {
    __shared__ int tmp[512];
    int t = threadIdx.x;
    int v = (t < nb) ? bsum[t] : 0;
    tmp[t] = v;
    __syncthreads();
    for (int off = 1; off < 512; off <<= 1) {
        int u = (t >= off) ? tmp[t - off] : 0;
        __syncthreads();
        tmp[t] += u;
        __syncthreads();
    }
    if (t < nb) boff[t] = tmp[t] - v;   // exclusive
}

// ---- scan step 3: per-block scan -> rowptr, dinv, per-copy bases rp2 ----
__global__ __launch_bounds__(256) void k_scanfinal(const int* __restrict__ deg8,
                                                   const int* __restrict__ boff,
                                                   int* __restrict__ rowptr,
                                                   float* __restrict__ dinv,
                                                   int* __restrict__ rp2) {  // [NC][N]
    __shared__ int tmp[256];
    int i = blockIdx.x * 256 + threadIdx.x;
    int t = threadIdx.x;
    int vc[NC];
    int v = 0;
    if (i < N_NODES) {
        #pragma unroll
        for (int c = 0; c < NC; ++c) { vc[c] = deg8[(size_t)c * N_NODES + i]; v += vc[c]; }
    } else {
        #pragma unroll
        for (int c = 0; c < NC; ++c) vc[c] = 0;
    }
    tmp[t] = v;
    __syncthreads();
    for (int off = 1; off < 256; off <<= 1) {
        int u = (t >= off) ? tmp[t - off] : 0;
        __syncthreads();
        tmp[t] += u;
        __syncthreads();
    }
    int excl = boff[blockIdx.x] + tmp[t] - v;
    if (i < N_NODES) {
        rowptr[i] = excl;
        dinv[i] = 1.0f / sqrtf((float)v + 1.0f);
        int run = excl;
        #pragma unroll
        for (int c = 0; c < NC; ++c) { rp2[(size_t)c * N_NODES + i] = run; run += vc[c]; }
    }
    if (blockIdx.x == 0 && t == 0) rowptr[N_NODES] = N_EDGES;
}

// ---- CSR fill, atomic-free, ILP-2: eidx[rp2[c][dst] + rank] = src ----
__global__ __launch_bounds__(256) void k_fill(const int* __restrict__ src,
                                              const int* __restrict__ dst,
                                              const int* __restrict__ rank,
                                              const int* __restrict__ rp2,
                                              int* __restrict__ eidx) {
    int base = (blockIdx.x * 256 + threadIdx.x) * 2;
    if (base < N_EDGES) {     // N_EDGES % 2 == 0; base,base+1 share copy c
        int2 s2 = *(const int2*)&src[base];
        int2 d2 = *(const int2*)&dst[base];
        int2 r2 = *(const int2*)&rank[base];
        int c = (base >> 10) & (NC - 1);
        const int* rp = rp2 + (size_t)c * N_NODES;
        eidx[rp[d2.x] + r2.x] = s2.x;
        eidx[rp[d2.y] + r2.y] = s2.y;
    }
}

// ---- fused: gather L1 (fp16 h) -> relu -> LDS -> gemm x W2 -> pre-scaled fp16 ----
__global__ __launch_bounds__(256) void k_gathergemm(const __half* __restrict__ h16,
                                                    const int* __restrict__ eidx,
                                                    const int* __restrict__ rowptr,
                                                    const float* __restrict__ dinv,
                                                    const float* __restrict__ bias,
                                                    const float* __restrict__ W2,
                                                    __half* __restrict__ Hout16) {
    __shared__ float Xl[64][66];
    __shared__ float Wl[64 * 64];
    const int tid  = threadIdx.x;
    const int ng4  = tid >> 4;
    const int tile = blockIdx.x;
    const int c4   = (tid & 15) * 4;

    // stage W2 (16KB) while gather loads are in flight
    for (int i = tid; i < 64 * 16; i += 256)
        ((float4*)Wl)[i] = ((const float4*)W2)[i];

    float4 b = *(const float4*)&bias[c4];
    #pragma unroll
    for (int j = 0; j < 4; ++j) {
        int node = tile * 64 + ng4 * 4 + j;
        float4 r = make_float4(0.f, 0.f, 0.f, 0.f);
        if (node < N_NODES) {
            int e0 = rowptr[node], e1 = rowptr[node + 1];
            float4 acc = gather_row_w(h16, eidx, dinv, e0, e1, c4);
            float di = dinv[node];
            float4 hd = ldh4(&h16[(size_t)node * HID + c4]);
            // z = relu(di*(acc + di*hd) + b)
            r.x = fmaxf(fmaf(di, fmaf(di, hd.x, acc.x), b.x), 0.f);
            r.y = fmaxf(fmaf(di, fmaf(di, hd.y, acc.y), b.y), 0.f);
            r.z = fmaxf(fmaf(di, fmaf(di, hd.z, acc.z), b.z), 0.f);
            r.w = fmaxf(fmaf(di, fmaf(di, hd.w, acc.w), b.w), 0.f);
        }
        *(float4*)&Xl[ng4 * 4 + j][c4] = r;
    }
    __syncthreads();

    // gemm from LDS; epilogue pre-scales by dinv[row] for layer-2 gather
    float4 a0 = {0,0,0,0}, a1 = {0,0,0,0}, a2 = {0,0,0,0}, a3 = {0,0,0,0};
    #pragma unroll 4
    for (int k2 = 0; k2 < 64; k2 += 4) {
        float4 w0 = *(float4*)&Wl[(k2 + 0) * 64 + c4];
        float4 w1 = *(float4*)&Wl[(k2 + 1) * 64 + c4];
        float4 w2 = *(float4*)&Wl[(k2 + 2) * 64 + c4];
        float4 w3 = *(float4*)&Wl[(k2 + 3) * 64 + c4];
        float4 x0 = *(float4*)&Xl[ng4 * 4 + 0][k2];
        float4 x1 = *(float4*)&Xl[ng4 * 4 + 1][k2];
        float4 x2 = *(float4*)&Xl[ng4 * 4 + 2][k2];
        float4 x3 = *(float4*)&Xl[ng4 * 4 + 3][k2];
        FMA_ROW(a0, x0);
        FMA_ROW(a1, x1);
        FMA_ROW(a2, x2);
        FMA_ROW(a3, x3);
    }

    const int r0 = tile * 64 + ng4 * 4;
    if (r0 + 0 < N_NODES) { float d0 = dinv[r0 + 0];
        a0.x *= d0; a0.y *= d0; a0.z *= d0; a0.w *= d0;
        sth4(&Hout16[(size_t)(r0 + 0) * HID + c4], a0); }
    if (r0 + 1 < N_NODES) { float d1 = dinv[r0 + 1];
        a1.x *= d1; a1.y *= d1; a1.z *= d1; a1.w *= d1;
        sth4(&Hout16[(size_t)(r0 + 1) * HID + c4], a1); }
    if (r0 + 2 < N_NODES) { float d2 = dinv[r0 + 2];
        a2.x *= d2; a2.y *= d2; a2.z *= d2; a2.w *= d2;
        sth4(&Hout16[(size_t)(r0 + 2) * HID + c4], a2); }
    if (r0 + 3 < N_NODES) { float d3 = dinv[r0 + 3];
        a3.x *= d3; a3.y *= d3; a3.z *= d3; a3.w *= d3;
        sth4(&Hout16[(size_t)(r0 + 3) * HID + c4], a3); }
}

// ---- fused: gather L2 (pre-scaled fp16) -> relu -> LDS -> run-length pool ----
__global__ __launch_bounds__(256) void k_gatherpool(const __half* __restrict__ hw16,
                                                    const int* __restrict__ eidx,
                                                    const int* __restrict__ rowptr,
                                                    const float* __restrict__ dinv,
                                                    const float* __restrict__ bias,
                                                    const int* __restrict__ batch,
                                                    float* __restrict__ gsum) {
    __shared__ float Xl[64][66];
    __shared__ int bl[64];
    const int tid  = threadIdx.x;
    const int ng4  = tid >> 4;
    const int tile = blockIdx.x;
    const int c4   = (tid & 15) * 4;

    if (tid < 64) {
        int node = tile * 64 + tid;
        bl[tid] = (node < N_NODES) ? batch[node] : -1;
    }

    float4 b = *(const float4*)&bias[c4];
    #pragma unroll
    for (int j = 0; j < 4; ++j) {
        int node = tile * 64 + ng4 * 4 + j;
        float4 r = make_float4(0.f, 0.f, 0.f, 0.f);
        if (node < N_NODES) {
            int e0 = rowptr[node], e1 = rowptr[node + 1];
            float4 acc = gather_row_nw(hw16, eidx, e0, e1, c4);
            float di = dinv[node];
            float4 hw = ldh4(&hw16[(size_t)node * HID + c4]);
            // h2 = relu(di*(acc + hw) + b)   (hw rows pre-scaled by dinv[src])
            r.x = fmaxf(fmaf(di, acc.x + hw.x, b.x), 0.f);
            r.y = fmaxf(fmaf(di, acc.y + hw.y, b.y), 0.f);
            r.z = fmaxf(fmaf(di, acc.z + hw.z, b.z), 0.f);
            r.w = fmaxf(fmaf(di, acc.w + hw.w, b.w), 0.f);
        }
        *(float4*)&Xl[ng4 * 4 + j][c4] = r;
    }
    __syncthreads();

    // pool: 64 column-threads, run-length over sorted batch
    if (tid < 64) {
        int c = tid;
        float acc = 0.f;
        int gprev = bl[0];
        #pragma unroll 8
        for (int n = 0; n < 64; ++n) {
            int g = bl[n];
            if (g < 0) break;
            if (g != gprev) {
                unsafeAtomicAdd(&gsum[gprev * HID + c], acc);
                acc = 0.f;
                gprev = g;
            }
            acc += Xl[n][c];
        }
        if (gprev >= 0) unsafeAtomicAdd(&gsum[gprev * HID + c], acc);
    }
}

// ---------------- head: out[g] = (gsum[g]/cnt) . Wout + bout ----------------
__global__ void k_out(const float* __restrict__ gsum, const int* __restrict__ gcnt,
                      const float* __restrict__ Wout, const float* __restrict__ bout,
                      float* __restrict__ out) {
    int g = threadIdx.x;
    if (g >= NG) return;
    float acc = 0.f;
    for (int c = 0; c < HID; ++c) acc += gsum[g * HID + c] * Wout[c];
    float cnt = fmaxf((float)gcnt[g], 1.0f);
    out[g] = acc / cnt + bout[0];
}

extern "C" void kernel_launch(void* const* d_in, const int* in_sizes, int n_in,
                              void* d_out, int out_size, void* d_ws, size_t ws_size,
                              hipStream_t stream) {
    const float* x    = (const float*)d_in[0];
    const int*   ei   = (const int*)d_in[1];
    const int*   batch= (const int*)d_in[2];
    const float* W1   = (const float*)d_in[3];
    const float* b1   = (const float*)d_in[4];
    const float* W2   = (const float*)d_in[5];
    const float* b2   = (const float*)d_in[6];
    const float* Wout = (const float*)d_in[7];
    const float* bout = (const float*)d_in[8];
    float* out = (float*)d_out;

    const int* src  = ei;
    const int* dstp = ei + N_EDGES;

    char* w = (char*)d_ws;
    int*    deg8  = (int*)w;    w += (size_t)NC * N_NODES * 4;
    int*    rp2   = (int*)w;    w += (size_t)NC * N_NODES * 4;
    int*    gcnt  = (int*)w;    w += (size_t)NG * 4;
    int*    bsum  = (int*)w;    w += (size_t)512 * 4;
    int*    boff  = (int*)w;    w += (size_t)512 * 4;
    int*    rowptr= (int*)w;    w += (size_t)(N_NODES + 4) * 4;
    float*  dinv  = (float*)w;  w += (size_t)N_NODES * 4;
    float*  gsum  = (float*)w;  w += (size_t)NG * HID * 4;
    int*    rank  = (int*)w;    w += (size_t)N_EDGES * 4;
    int*    eidx  = (int*)w;    w += (size_t)N_EDGES * 4;
    __half* bufA16= (__half*)w; w += (size_t)N_NODES * HID * 2;
    __half* bufB16= (__half*)w; w += (size_t)N_NODES * HID * 2;

    hipMemsetAsync(deg8, 0, (size_t)NC * N_NODES * 4, stream);
    hipMemsetAsync(gcnt, 0, (size_t)NG * 4, stream);
    hipMemsetAsync(gsum, 0, (size_t)NG * HID * 4, stream);

    // fused: gemm1 (fp16 out) || ILP-4 NC-way deg histogram+rank || counts
    k_front<<<GEMB + DEGB4 + CNTB, 256, 0, stream>>>(dstp, deg8, rank, batch, gcnt,
                                                     x, W1, bufA16);
    // CSR scan + fill
    k_blocksum <<<NB, 256, 0, stream>>>(deg8, bsum);
    k_scanb    <<<1, 512, 0, stream>>>(bsum, boff, NB);
    k_scanfinal<<<NB, 256, 0, stream>>>(deg8, boff, rowptr, dinv, rp2);
    k_fill     <<<(N_EDGES / 2 + 255) / 256, 256, 0, stream>>>(src, dstp, rank, rp2, eidx);

    // Layer-1 aggregation fused with layer-2 GEMM (writes pre-scaled fp16)
    k_gathergemm<<<GEMB, 256, 0, stream>>>(bufA16, eidx, rowptr, dinv, b1, W2, bufB16);

    // Layer-2 aggregation fused with mean-pool partials
    k_gatherpool<<<GEMB, 256, 0, stream>>>(bufB16, eidx, rowptr, dinv, b2, batch, gsum);

    // head
    k_out<<<1, 128, 0, stream>>>(gsum, gcnt, Wout, bout, out);
}

// Round 12
// 274.477 us; speedup vs baseline: 4.2859x; 4.2859x over previous
//
#include <hip/hip_runtime.h>
#include <hip/hip_fp16.h>

#define N_NODES 100000
#define N_EDGES 1600000
#define F_IN 128
#define HID 64
#define NG 128

#define GEMB 1563   // 64-row tiles: ceil(100000/64)
#define DEGB4 1563  // hist blocks, 4 edges/thread: ceil(1.6M/1024)
#define CNTB 391    // ceil(100K/256)
#define NB   391    // scan blocks over nodes

// 16 fp32 FMAs: acc(4 cols) += xv(4 k-vals) * w0..w3 (rows of W chunk)
#define FMA_ROW(acc, xv) \
    acc.x = fmaf(xv.x, w0.x, acc.x); acc.y = fmaf(xv.x, w0.y, acc.y); \
    acc.z = fmaf(xv.x, w0.z, acc.z); acc.w = fmaf(xv.x, w0.w, acc.w); \
    acc.x = fmaf(xv.y, w1.x, acc.x); acc.y = fmaf(xv.y, w1.y, acc.y); \
    acc.z = fmaf(xv.y, w1.z, acc.z); acc.w = fmaf(xv.y, w1.w, acc.w); \
    acc.x = fmaf(xv.z, w2.x, acc.x); acc.y = fmaf(xv.z, w2.y, acc.y); \
    acc.z = fmaf(xv.z, w2.z, acc.z); acc.w = fmaf(xv.z, w2.w, acc.w); \
    acc.x = fmaf(xv.w, w3.x, acc.x); acc.y = fmaf(xv.w, w3.y, acc.y); \
    acc.z = fmaf(xv.w, w3.z, acc.z); acc.w = fmaf(xv.w, w3.w, acc.w);

#define FMA_EDGE(hh, ww) \
    acc.x = fmaf(hh.x, ww, acc.x); acc.y = fmaf(hh.y, ww, acc.y); \
    acc.z = fmaf(hh.z, ww, acc.z); acc.w = fmaf(hh.w, ww, acc.w);

#define ADD_EDGE(hh) \
    acc.x += hh.x; acc.y += hh.y; acc.z += hh.z; acc.w += hh.w;

// ---- fp16x4 load/store helpers (8B) ----
__device__ __forceinline__ float4 ldh4(const __half* p) {
    uint2 u = *(const uint2*)p;
    __half2 a = *(__half2*)&u.x, b = *(__half2*)&u.y;
    float2 fa = __half22float2(a), fb = __half22float2(b);
    return make_float4(fa.x, fa.y, fb.x, fb.y);
}
__device__ __forceinline__ void sth4(__half* p, float4 v) {
    __half2 a = __floats2half2_rn(v.x, v.y), b = __floats2half2_rn(v.z, v.w);
    uint2 u; u.x = *(unsigned int*)&a; u.y = *(unsigned int*)&b;
    *(uint2*)p = u;
}

// ---- edge-sum, layer1 (weighted): sum_e dinv[s]*h16[s][c4..c4+3] ----
__device__ __forceinline__ float4 gather_row_w(const __half* __restrict__ h16,
                                               const int* __restrict__ eidx,
                                               const float* __restrict__ dinv,
                                               int e0, int e1, int c4) {
    float4 acc = make_float4(0.f, 0.f, 0.f, 0.f);
    int e = e0;
    for (; e + 7 < e1; e += 8) {
        int s0 = eidx[e],     s1 = eidx[e + 1], s2 = eidx[e + 2], s3 = eidx[e + 3];
        int s4 = eidx[e + 4], s5 = eidx[e + 5], s6 = eidx[e + 6], s7 = eidx[e + 7];
        float w0 = dinv[s0], w1 = dinv[s1], w2 = dinv[s2], w3 = dinv[s3];
        float w4 = dinv[s4], w5 = dinv[s5], w6 = dinv[s6], w7 = dinv[s7];
        float4 h0 = ldh4(&h16[(size_t)s0 * HID + c4]);
        float4 h1 = ldh4(&h16[(size_t)s1 * HID + c4]);
        float4 h2 = ldh4(&h16[(size_t)s2 * HID + c4]);
        float4 h3 = ldh4(&h16[(size_t)s3 * HID + c4]);
        float4 h4 = ldh4(&h16[(size_t)s4 * HID + c4]);
        float4 h5 = ldh4(&h16[(size_t)s5 * HID + c4]);
        float4 h6 = ldh4(&h16[(size_t)s6 * HID + c4]);
        float4 h7 = ldh4(&h16[(size_t)s7 * HID + c4]);
        FMA_EDGE(h0, w0); FMA_EDGE(h1, w1); FMA_EDGE(h2, w2); FMA_EDGE(h3, w3);
        FMA_EDGE(h4, w4); FMA_EDGE(h5, w5); FMA_EDGE(h6, w6); FMA_EDGE(h7, w7);
    }
    if (e + 3 < e1) {
        int s0 = eidx[e], s1 = eidx[e + 1], s2 = eidx[e + 2], s3 = eidx[e + 3];
        float w0 = dinv[s0], w1 = dinv[s1], w2 = dinv[s2], w3 = dinv[s3];
        float4 h0 = ldh4(&h16[(size_t)s0 * HID + c4]);
        float4 h1 = ldh4(&h16[(size_t)s1 * HID + c4]);
        float4 h2 = ldh4(&h16[(size_t)s2 * HID + c4]);
        float4 h3 = ldh4(&h16[(size_t)s3 * HID + c4]);
        FMA_EDGE(h0, w0); FMA_EDGE(h1, w1); FMA_EDGE(h2, w2); FMA_EDGE(h3, w3);
        e += 4;
    }
    for (; e < e1; ++e) {
        int s0 = eidx[e];
        float w0 = dinv[s0];
        float4 h0 = ldh4(&h16[(size_t)s0 * HID + c4]);
        FMA_EDGE(h0, w0);
    }
    return acc;
}

// ---- edge-sum, layer2 (pre-scaled rows): sum_e hw16[s][c4..c4+3] ----
__device__ __forceinline__ float4 gather_row_nw(const __half* __restrict__ h16,
                                                const int* __restrict__ eidx,
                                                int e0, int e1, int c4) {
    float4 acc = make_float4(0.f, 0.f, 0.f, 0.f);
    int e = e0;
    for (; e + 7 < e1; e += 8) {
        int s0 = eidx[e],     s1 = eidx[e + 1], s2 = eidx[e + 2], s3 = eidx[e + 3];
        int s4 = eidx[e + 4], s5 = eidx[e + 5], s6 = eidx[e + 6], s7 = eidx[e + 7];
        float4 h0 = ldh4(&h16[(size_t)s0 * HID + c4]);
        float4 h1 = ldh4(&h16[(size_t)s1 * HID + c4]);
        float4 h2 = ldh4(&h16[(size_t)s2 * HID + c4]);
        float4 h3 = ldh4(&h16[(size_t)s3 * HID + c4]);
        float4 h4 = ldh4(&h16[(size_t)s4 * HID + c4]);
        float4 h5 = ldh4(&h16[(size_t)s5 * HID + c4]);
        float4 h6 = ldh4(&h16[(size_t)s6 * HID + c4]);
        float4 h7 = ldh4(&h16[(size_t)s7 * HID + c4]);
        ADD_EDGE(h0); ADD_EDGE(h1); ADD_EDGE(h2); ADD_EDGE(h3);
        ADD_EDGE(h4); ADD_EDGE(h5); ADD_EDGE(h6); ADD_EDGE(h7);
    }
    if (e + 3 < e1) {
        int s0 = eidx[e], s1 = eidx[e + 1], s2 = eidx[e + 2], s3 = eidx[e + 3];
        float4 h0 = ldh4(&h16[(size_t)s0 * HID + c4]);
        float4 h1 = ldh4(&h16[(size_t)s1 * HID + c4]);
        float4 h2 = ldh4(&h16[(size_t)s2 * HID + c4]);
        float4 h3 = ldh4(&h16[(size_t)s3 * HID + c4]);
        ADD_EDGE(h0); ADD_EDGE(h1); ADD_EDGE(h2); ADD_EDGE(h3);
        e += 4;
    }
    for (; e < e1; ++e) {
        int s0 = eidx[e];
        float4 h0 = ldh4(&h16[(size_t)s0 * HID + c4]);
        ADD_EDGE(h0);
    }
    return acc;
}

// ---- 64x64 GEMM tile -> fp16 output, W staged in 16KB LDS halves ----
// (R10 version; natural VGPR allocation ~96 — do NOT clamp, R11 lesson)
template <int K>
__device__ __forceinline__ void gemm_tile(const float* __restrict__ X,
                                          const float* __restrict__ W,
                                          __half* __restrict__ H16,
                                          int tile, float* smem) {
    const int tid = threadIdx.x;
    const int rg  = tid >> 4;
    const int c4  = (tid & 15) * 4;
    const int r0  = tile * 64 + rg * 4;
    const bool full = (r0 + 3 < N_NODES);

    float4 a0 = {0,0,0,0}, a1 = {0,0,0,0}, a2 = {0,0,0,0}, a3 = {0,0,0,0};

    for (int kh = 0; kh < K; kh += 64) {
        __syncthreads();
        for (int i = tid; i < 1024; i += 256)
            ((float4*)smem)[i] = ((const float4*)(W + kh * 64))[i];
        __syncthreads();

        const float* Xb = X + (size_t)r0 * K + kh;
        #pragma unroll 4
        for (int k2 = 0; k2 < 64; k2 += 4) {
            float4 w0 = *(float4*)&smem[(k2 + 0) * 64 + c4];
            float4 w1 = *(float4*)&smem[(k2 + 1) * 64 + c4];
            float4 w2 = *(float4*)&smem[(k2 + 2) * 64 + c4];
            float4 w3 = *(float4*)&smem[(k2 + 3) * 64 + c4];
            float4 x0 = {0,0,0,0}, x1 = {0,0,0,0}, x2 = {0,0,0,0}, x3 = {0,0,0,0};
            if (full) {
                x0 = *(const float4*)&Xb[0 * (size_t)K + k2];
                x1 = *(const float4*)&Xb[1 * (size_t)K + k2];
                x2 = *(const float4*)&Xb[2 * (size_t)K + k2];
                x3 = *(const float4*)&Xb[3 * (size_t)K + k2];
            } else {
                if (r0 + 0 < N_NODES) x0 = *(const float4*)&Xb[0 * (size_t)K + k2];
                if (r0 + 1 < N_NODES) x1 = *(const float4*)&Xb[1 * (size_t)K + k2];
                if (r0 + 2 < N_NODES) x2 = *(const float4*)&Xb[2 * (size_t)K + k2];
                if (r0 + 3 < N_NODES) x3 = *(const float4*)&Xb[3 * (size_t)K + k2];
            }
            FMA_ROW(a0, x0);
            FMA_ROW(a1, x1);
            FMA_ROW(a2, x2);
            FMA_ROW(a3, x3);
        }
    }

    if (full) {
        sth4(&H16[(size_t)(r0 + 0) * HID + c4], a0);
        sth4(&H16[(size_t)(r0 + 1) * HID + c4], a1);
        sth4(&H16[(size_t)(r0 + 2) * HID + c4], a2);
        sth4(&H16[(size_t)(r0 + 3) * HID + c4], a3);
    } else {
        if (r0 + 0 < N_NODES) sth4(&H16[(size_t)(r0 + 0) * HID + c4], a0);
        if (r0 + 1 < N_NODES) sth4(&H16[(size_t)(r0 + 1) * HID + c4], a1);
        if (r0 + 2 < N_NODES) sth4(&H16[(size_t)(r0 + 2) * HID + c4], a2);
        if (r0 + 3 < N_NODES) sth4(&H16[(size_t)(r0 + 3) * HID + c4], a3);
    }
}

// ---- fused front: [gemm1 | ILP-4 deg histogram + rank | counts] ----
// NO launch-bounds clamp (R11: forcing 64 VGPR spilled gemm to scratch, 4x regression)
__global__ __launch_bounds__(256) void k_front(const int* __restrict__ dst,
                                               int* __restrict__ deg,
                                               int* __restrict__ rank,
                                               const int* __restrict__ batch,
                                               int* __restrict__ gcnt,
                                               const float* __restrict__ X,
                                               const float* __restrict__ W,
                                               __half* __restrict__ H16) {
    __shared__ float smem[4096];   // 16 KB: gemm W-stage / count bins
    int bid = blockIdx.x;
    if (bid < GEMB) {
        gemm_tile<F_IN>(X, W, H16, bid, smem);
    } else if (bid < GEMB + DEGB4) {
        int base = ((bid - GEMB) * 256 + threadIdx.x) * 4;
        if (base < N_EDGES) {             // N_EDGES % 4 == 0 -> full int4 ok
            int4 d4 = *(const int4*)&dst[base];
            int r0 = atomicAdd(&deg[d4.x], 1);
            int r1 = atomicAdd(&deg[d4.y], 1);
            int r2 = atomicAdd(&deg[d4.z], 1);
            int r3 = atomicAdd(&deg[d4.w], 1);
            *(int4*)&rank[base] = make_int4(r0, r1, r2, r3);
        }
    } else {
        int* bins = (int*)smem;
        if (threadIdx.x < NG) bins[threadIdx.x] = 0;
        __syncthreads();
        int i = (bid - GEMB - DEGB4) * 256 + threadIdx.x;
        if (i < N_NODES) atomicAdd(&bins[batch[i]], 1);
        __syncthreads();
        if (threadIdx.x < NG && bins[threadIdx.x] != 0)
            atomicAdd(&gcnt[threadIdx.x], bins[threadIdx.x]);
    }
}

// ---------------- scan step 1: per-block sums of deg ----------------
__global__ __launch_bounds__(256) void k_blocksum(const int* __restrict__ deg,
                                                  int* __restrict__ bsum) {
    __shared__ int red[256];
    int i = blockIdx.x * 256 + threadIdx.x;
    red[threadIdx.x] = (i < N_NODES) ? deg[i] : 0;
    __syncthreads();
    for (int off = 128; off > 0; off >>= 1) {
        if (threadIdx.x < off) red[threadIdx.x] += red[threadIdx.x + off];
        __syncthreads();
    }
    if (threadIdx.x == 0) bsum[blockIdx.x] = red[0];
}

// ---------------- scan step 2: exclusive scan of block sums ----------------
__global__ __launch_bounds__(512) void k_scanb(const int* __restrict__ bsum,
                                               int* __restrict__ boff, int nb) {
    __shared__ int tmp[512];
    int t = threadIdx.x;
    int v = (t < nb) ? bsum[t] : 0;
    tmp[t] = v;
    __syncthreads();
    for (int off = 1; off < 512; off <<= 1) {
        int u = (t >= off) ? tmp[t - off] : 0;
        __syncthreads();
        tmp[t] += u;
        __syncthreads();
    }
    if (t < nb) boff[t] = tmp[t] - v;   // exclusive
}

// ---- scan step 3: per-block scan + offset -> rowptr, dinv ----
__global__ __launch_bounds__(256) void k_scanfinal(const int* __restrict__ deg,
                                                   const int* __restrict__ boff,
                                                   int* __restrict__ rowptr,
                                                   float* __restrict__ dinv) {
    __shared__ int tmp[256];
    int i = blockIdx.x * 256 + threadIdx.x;
    int t = threadIdx.x;
    int v = (i < N_NODES) ? deg[i] : 0;
    tmp[t] = v;
    __syncthreads();
    for (int off = 1; off < 256; off <<= 1) {
        int u = (t >= off) ? tmp[t - off] : 0;
        __syncthreads();
        tmp[t] += u;
        __syncthreads();
    }
    int excl = boff[blockIdx.x] + tmp[t] - v;
    if (i < N_NODES) {
        rowptr[i] = excl;
        dinv[i] = 1.0f / sqrtf((float)v + 1.0f);
    }
    if (blockIdx.x == 0 && t == 0) rowptr[N_NODES] = N_EDGES;
}

// ---- CSR fill, atomic-free: eidx[rowptr[dst]+rank] = src ----
__global__ __launch_bounds__(256) void k_fill(const int* __restrict__ src,
                                              const int* __restrict__ dst,
                                              const int* __restrict__ rank,
                                              const int* __restrict__ rowptr,
                                              int* __restrict__ eidx) {
    int e = blockIdx.x * 256 + threadIdx.x;
    if (e < N_EDGES) {
        eidx[rowptr[dst[e]] + rank[e]] = src[e];
    }
}

// ---- fused: gather L1 (fp16 h) -> relu -> LDS -> gemm x W2 -> pre-scaled fp16 ----
__global__ __launch_bounds__(256) void k_gathergemm(const __half* __restrict__ h16,
                                                    const int* __restrict__ eidx,
                                                    const int* __restrict__ rowptr,
                                                    const float* __restrict__ dinv,
                                                    const float* __restrict__ bias,
                                                    const float* __restrict__ W2,
                                                    __half* __restrict__ Hout16) {
    __shared__ float Xl[64][66];
    __shared__ float Wl[64 * 64];
    const int tid  = threadIdx.x;
    const int ng4  = tid >> 4;
    const int tile = blockIdx.x;
    const int c4   = (tid & 15) * 4;

    // stage W2 (16KB) while gather loads are in flight
    for (int i = tid; i < 64 * 16; i += 256)
        ((float4*)Wl)[i] = ((const float4*)W2)[i];

    float4 b = *(const float4*)&bias[c4];
    #pragma unroll
    for (int j = 0; j < 4; ++j) {
        int node = tile * 64 + ng4 * 4 + j;
        float4 r = make_float4(0.f, 0.f, 0.f, 0.f);
        if (node < N_NODES) {
            int e0 = rowptr[node], e1 = rowptr[node + 1];
            float4 acc = gather_row_w(h16, eidx, dinv, e0, e1, c4);
            float di = dinv[node];
            float4 hd = ldh4(&h16[(size_t)node * HID + c4]);
            // z = relu(di*(acc + di*hd) + b)
            r.x = fmaxf(fmaf(di, fmaf(di, hd.x, acc.x), b.x), 0.f);
            r.y = fmaxf(fmaf(di, fmaf(di, hd.y, acc.y), b.y), 0.f);
            r.z = fmaxf(fmaf(di, fmaf(di, hd.z, acc.z), b.z), 0.f);
            r.w = fmaxf(fmaf(di, fmaf(di, hd.w, acc.w), b.w), 0.f);
        }
        *(float4*)&Xl[ng4 * 4 + j][c4] = r;
    }
    __syncthreads();

    // gemm from LDS; epilogue pre-scales by dinv[row] for layer-2 gather
    float4 a0 = {0,0,0,0}, a1 = {0,0,0,0}, a2 = {0,0,0,0}, a3 = {0,0,0,0};
    #pragma unroll 4
    for (int k2 = 0; k2 < 64; k2 += 4) {
        float4 w0 = *(float4*)&Wl[(k2 + 0) * 64 + c4];
        float4 w1 = *(float4*)&Wl[(k2 + 1) * 64 + c4];
        float4 w2 = *(float4*)&Wl[(k2 + 2) * 64 + c4];
        float4 w3 = *(float4*)&Wl[(k2 + 3) * 64 + c4];
        float4 x0 = *(float4*)&Xl[ng4 * 4 + 0][k2];
        float4 x1 = *(float4*)&Xl[ng4 * 4 + 1][k2];
        float4 x2 = *(float4*)&Xl[ng4 * 4 + 2][k2];
        float4 x3 = *(float4*)&Xl[ng4 * 4 + 3][k2];
        FMA_ROW(a0, x0);
        FMA_ROW(a1, x1);
        FMA_ROW(a2, x2);
        FMA_ROW(a3, x3);
    }

    const int r0 = tile * 64 + ng4 * 4;
    if (r0 + 0 < N_NODES) { float d0 = dinv[r0 + 0];
        a0.x *= d0; a0.y *= d0; a0.z *= d0; a0.w *= d0;
        sth4(&Hout16[(size_t)(r0 + 0) * HID + c4], a0); }
    if (r0 + 1 < N_NODES) { float d1 = dinv[r0 + 1];
        a1.x *= d1; a1.y *= d1; a1.z *= d1; a1.w *= d1;
        sth4(&Hout16[(size_t)(r0 + 1) * HID + c4], a1); }
    if (r0 + 2 < N_NODES) { float d2 = dinv[r0 + 2];
        a2.x *= d2; a2.y *= d2; a2.z *= d2; a2.w *= d2;
        sth4(&Hout16[(size_t)(r0 + 2) * HID + c4], a2); }
    if (r0 + 3 < N_NODES) { float d3 = dinv[r0 + 3];
        a3.x *= d3; a3.y *= d3; a3.z *= d3; a3.w *= d3;
        sth4(&Hout16[(size_t)(r0 + 3) * HID + c4], a3); }
}

// ---- fused: gather L2 (pre-scaled fp16) -> relu -> LDS -> run-length pool ----
__global__ __launch_bounds__(256) void k_gatherpool(const __half* __restrict__ hw16,
                                                    const int* __restrict__ eidx,
                                                    const int* __restrict__ rowptr,
                                                    const float* __restrict__ dinv,
                                                    const float* __restrict__ bias,
                                                    const int* __restrict__ batch,
                                                    float* __restrict__ gsum) {
    __shared__ float Xl[64][66];
    __shared__ int bl[64];
    const int tid  = threadIdx.x;
    const int ng4  = tid >> 4;
    const int tile = blockIdx.x;
    const int c4   = (tid & 15) * 4;

    if (tid < 64) {
        int node = tile * 64 + tid;
        bl[tid] = (node < N_NODES) ? batch[node] : -1;
    }

    float4 b = *(const float4*)&bias[c4];
    #pragma unroll
    for (int j = 0; j < 4; ++j) {
        int node = tile * 64 + ng4 * 4 + j;
        float4 r = make_float4(0.f, 0.f, 0.f, 0.f);
        if (node < N_NODES) {
            int e0 = rowptr[node], e1 = rowptr[node + 1];
            float4 acc = gather_row_nw(hw16, eidx, e0, e1, c4);
            float di = dinv[node];
            float4 hw = ldh4(&hw16[(size_t)node * HID + c4]);
            // h2 = relu(di*(acc + hw) + b)   (hw rows pre-scaled by dinv[src])
            r.x = fmaxf(fmaf(di, acc.x + hw.x, b.x), 0.f);
            r.y = fmaxf(fmaf(di, acc.y + hw.y, b.y), 0.f);
            r.z = fmaxf(fmaf(di, acc.z + hw.z, b.z), 0.f);
            r.w = fmaxf(fmaf(di, acc.w + hw.w, b.w), 0.f);
        }
        *(float4*)&Xl[ng4 * 4 + j][c4] = r;
    }
    __syncthreads();

    // pool: 64 column-threads, run-length over sorted batch
    if (tid < 64) {
        int c = tid;
        float acc = 0.f;
        int gprev = bl[0];
        #pragma unroll 8
        for (int n = 0; n < 64; ++n) {
            int g = bl[n];
            if (g < 0) break;
            if (g != gprev) {
                unsafeAtomicAdd(&gsum[gprev * HID + c], acc);
                acc = 0.f;
                gprev = g;
            }
            acc += Xl[n][c];
        }
        if (gprev >= 0) unsafeAtomicAdd(&gsum[gprev * HID + c], acc);
    }
}

// ---------------- head: out[g] = (gsum[g]/cnt) . Wout + bout ----------------
__global__ void k_out(const float* __restrict__ gsum, const int* __restrict__ gcnt,
                      const float* __restrict__ Wout, const float* __restrict__ bout,
                      float* __restrict__ out) {
    int g = threadIdx.x;
    if (g >= NG) return;
    float acc = 0.f;
    for (int c = 0; c < HID; ++c) acc += gsum[g * HID + c] * Wout[c];
    float cnt = fmaxf((float)gcnt[g], 1.0f);
    out[g] = acc / cnt + bout[0];
}

extern "C" void kernel_launch(void* const* d_in, const int* in_sizes, int n_in,
                              void* d_out, int out_size, void* d_ws, size_t ws_size,
                              hipStream_t stream) {
    const float* x    = (const float*)d_in[0];
    const int*   ei   = (const int*)d_in[1];
    const int*   batch= (const int*)d_in[2];
    const float* W1   = (const float*)d_in[3];
    const float* b1   = (const float*)d_in[4];
    const float* W2   = (const float*)d_in[5];
    const float* b2   = (const float*)d_in[6];
    const float* Wout = (const float*)d_in[7];
    const float* bout = (const float*)d_in[8];
    float* out = (float*)d_out;

    const int* src  = ei;
    const int* dstp = ei + N_EDGES;

    char* w = (char*)d_ws;
    int*    deg   = (int*)w;    w += (size_t)N_NODES * 4;
    int*    gcnt  = (int*)w;    w += (size_t)NG * 4;
    int*    bsum  = (int*)w;    w += (size_t)512 * 4;
    int*    boff  = (int*)w;    w += (size_t)512 * 4;
    int*    rowptr= (int*)w;    w += (size_t)(N_NODES + 4) * 4;
    float*  dinv  = (float*)w;  w += (size_t)N_NODES * 4;
    float*  gsum  = (float*)w;  w += (size_t)NG * HID * 4;
    int*    rank  = (int*)w;    w += (size_t)N_EDGES * 4;
    int*    eidx  = (int*)w;    w += (size_t)N_EDGES * 4;
    __half* bufA16= (__half*)w; w += (size_t)N_NODES * HID * 2;
    __half* bufB16= (__half*)w; w += (size_t)N_NODES * HID * 2;

    hipMemsetAsync(deg,  0, (size_t)N_NODES * 4, stream);
    hipMemsetAsync(gcnt, 0, (size_t)NG * 4, stream);
    hipMemsetAsync(gsum, 0, (size_t)NG * HID * 4, stream);

    // fused: gemm1 (fp16 out) || ILP-4 deg histogram+rank || counts
    k_front<<<GEMB + DEGB4 + CNTB, 256, 0, stream>>>(dstp, deg, rank, batch, gcnt,
                                                     x, W1, bufA16);
    // CSR scan + fill
    k_blocksum <<<NB, 256, 0, stream>>>(deg, bsum);
    k_scanb    <<<1, 512, 0, stream>>>(bsum, boff, NB);
    k_scanfinal<<<NB, 256, 0, stream>>>(deg, boff, rowptr, dinv);
    k_fill     <<<(N_EDGES + 255) / 256, 256, 0, stream>>>(src, dstp, rank, rowptr, eidx);

    // Layer-1 aggregation fused with layer-2 GEMM (writes pre-scaled fp16)
    k_gathergemm<<<GEMB, 256, 0, stream>>>(bufA16, eidx, rowptr, dinv, b1, W2, bufB16);

    // Layer-2 aggregation fused with mean-pool partials
    k_gatherpool<<<GEMB, 256, 0, stream>>>(bufB16, eidx, rowptr, dinv, b2, batch, gsum);

    // head
    k_out<<<1, 128, 0, stream>>>(gsum, gcnt, Wout, bout, out);
}

// Round 13
// 226.709 us; speedup vs baseline: 5.1889x; 1.2107x over previous
//
#include <hip/hip_runtime.h>
#include <hip/hip_fp16.h>

#define N_NODES 100000
#define N_EDGES 1600000
#define F_IN 128
#define HID 64
#define NG 128

#define GEMB 1563    // 64-row gemm tiles
#define NBINS 1024   // buckets = dst>>7 (782 used)
#define NBLK  391    // pass-A blocks, 4096 edges each
#define BUCKETS 782  // ceil(100000/128)
#define CNTB 391

#define FMA_ROW(acc, xv) \
    acc.x = fmaf(xv.x, w0.x, acc.x); acc.y = fmaf(xv.x, w0.y, acc.y); \
    acc.z = fmaf(xv.x, w0.z, acc.z); acc.w = fmaf(xv.x, w0.w, acc.w); \
    acc.x = fmaf(xv.y, w1.x, acc.x); acc.y = fmaf(xv.y, w1.y, acc.y); \
    acc.z = fmaf(xv.y, w1.z, acc.z); acc.w = fmaf(xv.y, w1.w, acc.w); \
    acc.x = fmaf(xv.z, w2.x, acc.x); acc.y = fmaf(xv.z, w2.y, acc.y); \
    acc.z = fmaf(xv.z, w2.z, acc.z); acc.w = fmaf(xv.z, w2.w, acc.w); \
    acc.x = fmaf(xv.w, w3.x, acc.x); acc.y = fmaf(xv.w, w3.y, acc.y); \
    acc.z = fmaf(xv.w, w3.z, acc.z); acc.w = fmaf(xv.w, w3.w, acc.w);

#define FMA_EDGE(hh, ww) \
    acc.x = fmaf(hh.x, ww, acc.x); acc.y = fmaf(hh.y, ww, acc.y); \
    acc.z = fmaf(hh.z, ww, acc.z); acc.w = fmaf(hh.w, ww, acc.w);

#define ADD_EDGE(hh) \
    acc.x += hh.x; acc.y += hh.y; acc.z += hh.z; acc.w += hh.w;

__device__ __forceinline__ float4 ldh4(const __half* p) {
    uint2 u = *(const uint2*)p;
    __half2 a = *(__half2*)&u.x, b = *(__half2*)&u.y;
    float2 fa = __half22float2(a), fb = __half22float2(b);
    return make_float4(fa.x, fa.y, fb.x, fb.y);
}
__device__ __forceinline__ void sth4(__half* p, float4 v) {
    __half2 a = __floats2half2_rn(v.x, v.y), b = __floats2half2_rn(v.z, v.w);
    uint2 u; u.x = *(unsigned int*)&a; u.y = *(unsigned int*)&b;
    *(uint2*)p = u;
}

__device__ __forceinline__ float4 gather_row_w(const __half* __restrict__ h16,
                                               const int* __restrict__ eidx,
                                               const float* __restrict__ dinv,
                                               int e0, int e1, int c4) {
    float4 acc = make_float4(0.f, 0.f, 0.f, 0.f);
    int e = e0;
    for (; e + 7 < e1; e += 8) {
        int s0 = eidx[e],     s1 = eidx[e + 1], s2 = eidx[e + 2], s3 = eidx[e + 3];
        int s4 = eidx[e + 4], s5 = eidx[e + 5], s6 = eidx[e + 6], s7 = eidx[e + 7];
        float w0 = dinv[s0], w1 = dinv[s1], w2 = dinv[s2], w3 = dinv[s3];
        float w4 = dinv[s4], w5 = dinv[s5], w6 = dinv[s6], w7 = dinv[s7];
        float4 h0 = ldh4(&h16[(size_t)s0 * HID + c4]);
        float4 h1 = ldh4(&h16[(size_t)s1 * HID + c4]);
        float4 h2 = ldh4(&h16[(size_t)s2 * HID + c4]);
        float4 h3 = ldh4(&h16[(size_t)s3 * HID + c4]);
        float4 h4 = ldh4(&h16[(size_t)s4 * HID + c4]);
        float4 h5 = ldh4(&h16[(size_t)s5 * HID + c4]);
        float4 h6 = ldh4(&h16[(size_t)s6 * HID + c4]);
        float4 h7 = ldh4(&h16[(size_t)s7 * HID + c4]);
        FMA_EDGE(h0, w0); FMA_EDGE(h1, w1); FMA_EDGE(h2, w2); FMA_EDGE(h3, w3);
        FMA_EDGE(h4, w4); FMA_EDGE(h5, w5); FMA_EDGE(h6, w6); FMA_EDGE(h7, w7);
    }
    if (e + 3 < e1) {
        int s0 = eidx[e], s1 = eidx[e + 1], s2 = eidx[e + 2], s3 = eidx[e + 3];
        float w0 = dinv[s0], w1 = dinv[s1], w2 = dinv[s2], w3 = dinv[s3];
        float4 h0 = ldh4(&h16[(size_t)s0 * HID + c4]);
        float4 h1 = ldh4(&h16[(size_t)s1 * HID + c4]);
        float4 h2 = ldh4(&h16[(size_t)s2 * HID + c4]);
        float4 h3 = ldh4(&h16[(size_t)s3 * HID + c4]);
        FMA_EDGE(h0, w0); FMA_EDGE(h1, w1); FMA_EDGE(h2, w2); FMA_EDGE(h3, w3);
        e += 4;
    }
    for (; e < e1; ++e) {
        int s0 = eidx[e];
        float w0 = dinv[s0];
        float4 h0 = ldh4(&h16[(size_t)s0 * HID + c4]);
        FMA_EDGE(h0, w0);
    }
    return acc;
}

__device__ __forceinline__ float4 gather_row_nw(const __half* __restrict__ h16,
                                                const int* __restrict__ eidx,
                                                int e0, int e1, int c4) {
    float4 acc = make_float4(0.f, 0.f, 0.f, 0.f);
    int e = e0;
    for (; e + 7 < e1; e += 8) {
        int s0 = eidx[e],     s1 = eidx[e + 1], s2 = eidx[e + 2], s3 = eidx[e + 3];
        int s4 = eidx[e + 4], s5 = eidx[e + 5], s6 = eidx[e + 6], s7 = eidx[e + 7];
        float4 h0 = ldh4(&h16[(size_t)s0 * HID + c4]);
        float4 h1 = ldh4(&h16[(size_t)s1 * HID + c4]);
        float4 h2 = ldh4(&h16[(size_t)s2 * HID + c4]);
        float4 h3 = ldh4(&h16[(size_t)s3 * HID + c4]);
        float4 h4 = ldh4(&h16[(size_t)s4 * HID + c4]);
        float4 h5 = ldh4(&h16[(size_t)s5 * HID + c4]);
        float4 h6 = ldh4(&h16[(size_t)s6 * HID + c4]);
        float4 h7 = ldh4(&h16[(size_t)s7 * HID + c4]);
        ADD_EDGE(h0); ADD_EDGE(h1); ADD_EDGE(h2); ADD_EDGE(h3);
        ADD_EDGE(h4); ADD_EDGE(h5); ADD_EDGE(h6); ADD_EDGE(h7);
    }
    if (e + 3 < e1) {
        int s0 = eidx[e], s1 = eidx[e + 1], s2 = eidx[e + 2], s3 = eidx[e + 3];
        float4 h0 = ldh4(&h16[(size_t)s0 * HID + c4]);
        float4 h1 = ldh4(&h16[(size_t)s1 * HID + c4]);
        float4 h2 = ldh4(&h16[(size_t)s2 * HID + c4]);
        float4 h3 = ldh4(&h16[(size_t)s3 * HID + c4]);
        ADD_EDGE(h0); ADD_EDGE(h1); ADD_EDGE(h2); ADD_EDGE(h3);
        e += 4;
    }
    for (; e < e1; ++e) {
        int s0 = eidx[e];
        float4 h0 = ldh4(&h16[(size_t)s0 * HID + c4]);
        ADD_EDGE(h0);
    }
    return acc;
}

template <int K>
__device__ __forceinline__ void gemm_tile(const float* __restrict__ X,
                                          const float* __restrict__ W,
                                          __half* __restrict__ H16,
                                          int tile, float* smem) {
    const int tid = threadIdx.x;
    const int rg  = tid >> 4;
    const int c4  = (tid & 15) * 4;
    const int r0  = tile * 64 + rg * 4;
    const bool full = (r0 + 3 < N_NODES);

    float4 a0 = {0,0,0,0}, a1 = {0,0,0,0}, a2 = {0,0,0,0}, a3 = {0,0,0,0};

    for (int kh = 0; kh < K; kh += 64) {
        __syncthreads();
        for (int i = tid; i < 1024; i += 256)
            ((float4*)smem)[i] = ((const float4*)(W + kh * 64))[i];
        __syncthreads();

        const float* Xb = X + (size_t)r0 * K + kh;
        #pragma unroll 4
        for (int k2 = 0; k2 < 64; k2 += 4) {
            float4 w0 = *(float4*)&smem[(k2 + 0) * 64 + c4];
            float4 w1 = *(float4*)&smem[(k2 + 1) * 64 + c4];
            float4 w2 = *(float4*)&smem[(k2 + 2) * 64 + c4];
            float4 w3 = *(float4*)&smem[(k2 + 3) * 64 + c4];
            float4 x0 = {0,0,0,0}, x1 = {0,0,0,0}, x2 = {0,0,0,0}, x3 = {0,0,0,0};
            if (full) {
                x0 = *(const float4*)&Xb[0 * (size_t)K + k2];
                x1 = *(const float4*)&Xb[1 * (size_t)K + k2];
                x2 = *(const float4*)&Xb[2 * (size_t)K + k2];
                x3 = *(const float4*)&Xb[3 * (size_t)K + k2];
            } else {
                if (r0 + 0 < N_NODES) x0 = *(const float4*)&Xb[0 * (size_t)K + k2];
                if (r0 + 1 < N_NODES) x1 = *(const float4*)&Xb[1 * (size_t)K + k2];
                if (r0 + 2 < N_NODES) x2 = *(const float4*)&Xb[2 * (size_t)K + k2];
                if (r0 + 3 < N_NODES) x3 = *(const float4*)&Xb[3 * (size_t)K + k2];
            }
            FMA_ROW(a0, x0);
            FMA_ROW(a1, x1);
            FMA_ROW(a2, x2);
            FMA_ROW(a3, x3);
        }
    }

    if (full) {
        sth4(&H16[(size_t)(r0 + 0) * HID + c4], a0);
        sth4(&H16[(size_t)(r0 + 1) * HID + c4], a1);
        sth4(&H16[(size_t)(r0 + 2) * HID + c4], a2);
        sth4(&H16[(size_t)(r0 + 3) * HID + c4], a3);
    } else {
        if (r0 + 0 < N_NODES) sth4(&H16[(size_t)(r0 + 0) * HID + c4], a0);
        if (r0 + 1 < N_NODES) sth4(&H16[(size_t)(r0 + 1) * HID + c4], a1);
        if (r0 + 2 < N_NODES) sth4(&H16[(size_t)(r0 + 2) * HID + c4], a2);
        if (r0 + 3 < N_NODES) sth4(&H16[(size_t)(r0 + 3) * HID + c4], a3);
    }
}

// ---- fused front: [gemm1 | LDS bucket-count (no global atomics) | batch counts] ----
__global__ __launch_bounds__(256) void k_front(const int* __restrict__ dst,
                                               int* __restrict__ hist,   // [NBINS][NBLK]
                                               const int* __restrict__ batch,
                                               int* __restrict__ gcnt,
                                               const float* __restrict__ X,
                                               const float* __restrict__ W,
                                               __half* __restrict__ H16) {
    __shared__ float smem[4096];   // 16 KB
    int bid = blockIdx.x;
    int tid = threadIdx.x;
    if (bid < GEMB) {
        gemm_tile<F_IN>(X, W, H16, bid, smem);
    } else if (bid < GEMB + NBLK) {
        int cb = bid - GEMB;
        int* bins = (int*)smem;
        for (int i = tid; i < NBINS; i += 256) bins[i] = 0;
        __syncthreads();
        #pragma unroll
        for (int it = 0; it < 4; ++it) {
            int base = cb * 4096 + it * 1024 + tid * 4;
            if (base < N_EDGES) {
                int4 d4 = *(const int4*)&dst[base];
                atomicAdd(&bins[d4.x >> 7], 1);
                atomicAdd(&bins[d4.y >> 7], 1);
                atomicAdd(&bins[d4.z >> 7], 1);
                atomicAdd(&bins[d4.w >> 7], 1);
            }
        }
        __syncthreads();
        for (int i = tid; i < NBINS; i += 256) hist[(size_t)i * NBLK + cb] = bins[i];
    } else {
        int* bins = (int*)smem;
        if (tid < NG) bins[tid] = 0;
        __syncthreads();
        int i = (bid - GEMB - NBLK) * 256 + tid;
        if (i < N_NODES) atomicAdd(&bins[batch[i]], 1);
        __syncthreads();
        if (tid < NG && bins[tid] != 0) atomicAdd(&gcnt[tid], bins[tid]);
    }
}

// ---- scan L1: 391 blocks x 1024 over hist (400384 = 391*1024 exactly) ----
__global__ __launch_bounds__(1024) void k_bsum(const int* __restrict__ hist,
                                               int* __restrict__ bsum) {
    __shared__ int red[1024];
    int i = blockIdx.x * 1024 + threadIdx.x;
    red[threadIdx.x] = hist[i];
    __syncthreads();
    for (int off = 512; off > 0; off >>= 1) {
        if (threadIdx.x < off) red[threadIdx.x] += red[threadIdx.x + off];
        __syncthreads();
    }
    if (threadIdx.x == 0) bsum[blockIdx.x] = red[0];
}

__global__ __launch_bounds__(512) void k_scanb(const int* __restrict__ bsum,
                                               int* __restrict__ boff, int nb) {
    __shared__ int tmp[512];
    int t = threadIdx.x;
    int v = (t < nb) ? bsum[t] : 0;
    tmp[t] = v;
    __syncthreads();
    for (int off = 1; off < 512; off <<= 1) {
        int u = (t >= off) ? tmp[t - off] : 0;
        __syncthreads();
        tmp[t] += u;
        __syncthreads();
    }
    if (t < nb) boff[t] = tmp[t] - v;
}

// ---- scan L3: in-place exclusive scan of hist; emit bucketstart ----
__global__ __launch_bounds__(1024) void k_scanfin(int* __restrict__ hist,
                                                  const int* __restrict__ boff,
                                                  int* __restrict__ bucketstart) {
    __shared__ int tmp[1024];
    int i = blockIdx.x * 1024 + threadIdx.x;
    int t = threadIdx.x;
    int v = hist[i];
    tmp[t] = v;
    __syncthreads();
    for (int off = 1; off < 1024; off <<= 1) {
        int u = (t >= off) ? tmp[t - off] : 0;
        __syncthreads();
        tmp[t] += u;
        __syncthreads();
    }
    int excl = boff[blockIdx.x] + tmp[t] - v;
    hist[i] = excl;
    if (i % NBLK == 0) bucketstart[i / NBLK] = excl;   // i = bin*NBLK
}

// ---- scatter: LDS cursors (atomic-return in LDS only) -> bucket-grouped recs ----
__global__ __launch_bounds__(256) void k_scatter(const int* __restrict__ src,
                                                 const int* __restrict__ dst,
                                                 const int* __restrict__ hist,
                                                 int* __restrict__ ebuf) {
    __shared__ int cur[NBINS];
    int cb = blockIdx.x;
    int tid = threadIdx.x;
    for (int i = tid; i < NBINS; i += 256) cur[i] = hist[(size_t)i * NBLK + cb];
    __syncthreads();
    #pragma unroll
    for (int it = 0; it < 4; ++it) {
        int base = cb * 4096 + it * 1024 + tid * 4;
        if (base < N_EDGES) {
            int4 s4 = *(const int4*)&src[base];
            int4 d4 = *(const int4*)&dst[base];
            int p0 = atomicAdd(&cur[d4.x >> 7], 1);
            int p1 = atomicAdd(&cur[d4.y >> 7], 1);
            int p2 = atomicAdd(&cur[d4.z >> 7], 1);
            int p3 = atomicAdd(&cur[d4.w >> 7], 1);
            ebuf[p0] = (s4.x << 7) | (d4.x & 127);
            ebuf[p1] = (s4.y << 7) | (d4.y & 127);
            ebuf[p2] = (s4.z << 7) | (d4.z & 127);
            ebuf[p3] = (s4.w << 7) | (d4.w & 127);
        }
    }
}

// ---- per-bucket CSR: stage recs in LDS, count/scan 128 nodes, place in-place ----
__global__ __launch_bounds__(256) void k_bucketcsr(int* __restrict__ eidx,   // = ebuf
                                                   const int* __restrict__ bucketstart,
                                                   int* __restrict__ rowptr,
                                                   float* __restrict__ dinv) {
    __shared__ int lrec[4096];
    __shared__ int lcnt[128];
    __shared__ int lsum[128];
    __shared__ int lcur[128];
    int b = blockIdx.x;
    int tid = threadIdx.x;
    int s0 = bucketstart[b], s1 = bucketstart[b + 1];
    int cnt = s1 - s0;

    if (tid < 128) lcnt[tid] = 0;
    __syncthreads();
    for (int i = tid; i < cnt; i += 256) {
        int r = eidx[s0 + i];
        lrec[i] = r;
        atomicAdd(&lcnt[r & 127], 1);
    }
    __syncthreads();
    if (tid < 128) lsum[tid] = lcnt[tid];
    __syncthreads();
    for (int off = 1; off < 128; off <<= 1) {
        int u = 0;
        if (tid < 128 && tid >= off) u = lsum[tid - off];
        __syncthreads();
        if (tid < 128) lsum[tid] += u;
        __syncthreads();
    }
    if (tid < 128) {
        int excl = lsum[tid] - lcnt[tid];        // exclusive prefix
        lcur[tid] = s0 + excl;
        int node = b * 128 + tid;
        if (node < N_NODES) {
            rowptr[node] = s0 + excl;
            dinv[node] = 1.0f / sqrtf((float)lcnt[tid] + 1.0f);
        }
    }
    __syncthreads();
    for (int i = tid; i < cnt; i += 256) {
        int r = lrec[i];
        int p = atomicAdd(&lcur[r & 127], 1);
        eidx[p] = r >> 7;
    }
    if (b == 0 && tid == 0) rowptr[N_NODES] = N_EDGES;
}

// ---- fused: gather L1 -> relu -> LDS -> gemm x W2 -> pre-scaled fp16 ----
__global__ __launch_bounds__(256) void k_gathergemm(const __half* __restrict__ h16,
                                                    const int* __restrict__ eidx,
                                                    const int* __restrict__ rowptr,
                                                    const float* __restrict__ dinv,
                                                    const float* __restrict__ bias,
                                                    const float* __restrict__ W2,
                                                    __half* __restrict__ Hout16) {
    __shared__ float Xl[64][66];
    __shared__ float Wl[64 * 64];
    const int tid  = threadIdx.x;
    const int ng4  = tid >> 4;
    const int tile = blockIdx.x;
    const int c4   = (tid & 15) * 4;

    for (int i = tid; i < 64 * 16; i += 256)
        ((float4*)Wl)[i] = ((const float4*)W2)[i];

    float4 b = *(const float4*)&bias[c4];
    #pragma unroll
    for (int j = 0; j < 4; ++j) {
        int node = tile * 64 + ng4 * 4 + j;
        float4 r = make_float4(0.f, 0.f, 0.f, 0.f);
        if (node < N_NODES) {
            int e0 = rowptr[node], e1 = rowptr[node + 1];
            float4 acc = gather_row_w(h16, eidx, dinv, e0, e1, c4);
            float di = dinv[node];
            float4 hd = ldh4(&h16[(size_t)node * HID + c4]);
            r.x = fmaxf(fmaf(di, fmaf(di, hd.x, acc.x), b.x), 0.f);
            r.y = fmaxf(fmaf(di, fmaf(di, hd.y, acc.y), b.y), 0.f);
            r.z = fmaxf(fmaf(di, fmaf(di, hd.z, acc.z), b.z), 0.f);
            r.w = fmaxf(fmaf(di, fmaf(di, hd.w, acc.w), b.w), 0.f);
        }
        *(float4*)&Xl[ng4 * 4 + j][c4] = r;
    }
    __syncthreads();

    float4 a0 = {0,0,0,0}, a1 = {0,0,0,0}, a2 = {0,0,0,0}, a3 = {0,0,0,0};
    #pragma unroll 4
    for (int k2 = 0; k2 < 64; k2 += 4) {
        float4 w0 = *(float4*)&Wl[(k2 + 0) * 64 + c4];
        float4 w1 = *(float4*)&Wl[(k2 + 1) * 64 + c4];
        float4 w2 = *(float4*)&Wl[(k2 + 2) * 64 + c4];
        float4 w3 = *(float4*)&Wl[(k2 + 3) * 64 + c4];
        float4 x0 = *(float4*)&Xl[ng4 * 4 + 0][k2];
        float4 x1 = *(float4*)&Xl[ng4 * 4 + 1][k2];
        float4 x2 = *(float4*)&Xl[ng4 * 4 + 2][k2];
        float4 x3 = *(float4*)&Xl[ng4 * 4 + 3][k2];
        FMA_ROW(a0, x0);
        FMA_ROW(a1, x1);
        FMA_ROW(a2, x2);
        FMA_ROW(a3, x3);
    }

    const int r0 = tile * 64 + ng4 * 4;
    if (r0 + 0 < N_NODES) { float d0 = dinv[r0 + 0];
        a0.x *= d0; a0.y *= d0; a0.z *= d0; a0.w *= d0;
        sth4(&Hout16[(size_t)(r0 + 0) * HID + c4], a0); }
    if (r0 + 1 < N_NODES) { float d1 = dinv[r0 + 1];
        a1.x *= d1; a1.y *= d1; a1.z *= d1; a1.w *= d1;
        sth4(&Hout16[(size_t)(r0 + 1) * HID + c4], a1); }
    if (r0 + 2 < N_NODES) { float d2 = dinv[r0 + 2];
        a2.x *= d2; a2.y *= d2; a2.z *= d2; a2.w *= d2;
        sth4(&Hout16[(size_t)(r0 + 2) * HID + c4], a2); }
    if (r0 + 3 < N_NODES) { float d3 = dinv[r0 + 3];
        a3.x *= d3; a3.y *= d3; a3.z *= d3; a3.w *= d3;
        sth4(&Hout16[(size_t)(r0 + 3) * HID + c4], a3); }
}

// ---- fused: gather L2 (pre-scaled) -> relu -> LDS -> run-length pool ----
__global__ __launch_bounds__(256) void k_gatherpool(const __half* __restrict__ hw16,
                                                    const int* __restrict__ eidx,
                                                    const int* __restrict__ rowptr,
                                                    const float* __restrict__ dinv,
                                                    const float* __restrict__ bias,
                                                    const int* __restrict__ batch,
                                                    float* __restrict__ gsum) {
    __shared__ float Xl[64][66];
    __shared__ int bl[64];
    const int tid  = threadIdx.x;
    const int ng4  = tid >> 4;
    const int tile = blockIdx.x;
    const int c4   = (tid & 15) * 4;

    if (tid < 64) {
        int node = tile * 64 + tid;
        bl[tid] = (node < N_NODES) ? batch[node] : -1;
    }

    float4 b = *(const float4*)&bias[c4];
    #pragma unroll
    for (int j = 0; j < 4; ++j) {
        int node = tile * 64 + ng4 * 4 + j;
        float4 r = make_float4(0.f, 0.f, 0.f, 0.f);
        if (node < N_NODES) {
            int e0 = rowptr[node], e1 = rowptr[node + 1];
            float4 acc = gather_row_nw(hw16, eidx, e0, e1, c4);
            float di = dinv[node];
            float4 hw = ldh4(&hw16[(size_t)node * HID + c4]);
            r.x = fmaxf(fmaf(di, acc.x + hw.x, b.x), 0.f);
            r.y = fmaxf(fmaf(di, acc.y + hw.y, b.y), 0.f);
            r.z = fmaxf(fmaf(di, acc.z + hw.z, b.z), 0.f);
            r.w = fmaxf(fmaf(di, acc.w + hw.w, b.w), 0.f);
        }
        *(float4*)&Xl[ng4 * 4 + j][c4] = r;
    }
    __syncthreads();

    if (tid < 64) {
        int c = tid;
        float acc = 0.f;
        int gprev = bl[0];
        #pragma unroll 8
        for (int n = 0; n < 64; ++n) {
            int g = bl[n];
            if (g < 0) break;
            if (g != gprev) {
                unsafeAtomicAdd(&gsum[gprev * HID + c], acc);
                acc = 0.f;
                gprev = g;
            }
            acc += Xl[n][c];
        }
        if (gprev >= 0) unsafeAtomicAdd(&gsum[gprev * HID + c], acc);
    }
}

__global__ void k_out(const float* __restrict__ gsum, const int* __restrict__ gcnt,
                      const float* __restrict__ Wout, const float* __restrict__ bout,
                      float* __restrict__ out) {
    int g = threadIdx.x;
    if (g >= NG) return;
    float acc = 0.f;
    for (int c = 0; c < HID; ++c) acc += gsum[g * HID + c] * Wout[c];
    float cnt = fmaxf((float)gcnt[g], 1.0f);
    out[g] = acc / cnt + bout[0];
}

extern "C" void kernel_launch(void* const* d_in, const int* in_sizes, int n_in,
                              void* d_out, int out_size, void* d_ws, size_t ws_size,
                              hipStream_t stream) {
    const float* x    = (const float*)d_in[0];
    const int*   ei   = (const int*)d_in[1];
    const int*   batch= (const int*)d_in[2];
    const float* W1   = (const float*)d_in[3];
    const float* b1   = (const float*)d_in[4];
    const float* W2   = (const float*)d_in[5];
    const float* b2   = (const float*)d_in[6];
    const float* Wout = (const float*)d_in[7];
    const float* bout = (const float*)d_in[8];
    float* out = (float*)d_out;

    const int* src  = ei;
    const int* dstp = ei + N_EDGES;

    char* w = (char*)d_ws;
    int*    hist  = (int*)w;    w += (size_t)NBINS * NBLK * 4;   // 1.6 MB
    int*    bstrt = (int*)w;    w += (size_t)(NBINS + 8) * 4;
    int*    gcnt  = (int*)w;    w += (size_t)NG * 4;
    int*    bsum  = (int*)w;    w += (size_t)512 * 4;
    int*    boff  = (int*)w;    w += (size_t)512 * 4;
    int*    rowptr= (int*)w;    w += (size_t)(N_NODES + 4) * 4;
    float*  dinv  = (float*)w;  w += (size_t)N_NODES * 4;
    float*  gsum  = (float*)w;  w += (size_t)NG * HID * 4;
    int*    eidx  = (int*)w;    w += (size_t)N_EDGES * 4;
    __half* bufA16= (__half*)w; w += (size_t)N_NODES * HID * 2;
    __half* bufB16= (__half*)w; w += (size_t)N_NODES * HID * 2;

    hipMemsetAsync(gcnt, 0, (size_t)NG * 4, stream);
    hipMemsetAsync(gsum, 0, (size_t)NG * HID * 4, stream);

    // fused: gemm1 || LDS bucket-count || batch counts  (zero global atomic-returns)
    k_front<<<GEMB + NBLK + CNTB, 256, 0, stream>>>(dstp, hist, batch, gcnt,
                                                    x, W1, bufA16);
    // linear exclusive scan of hist (400384 = 391*1024)
    k_bsum   <<<NBLK, 1024, 0, stream>>>(hist, bsum);
    k_scanb  <<<1, 512, 0, stream>>>(bsum, boff, NBLK);
    k_scanfin<<<NBLK, 1024, 0, stream>>>(hist, boff, bstrt);
    // bucket-grouped scatter (LDS atomic-returns only)
    k_scatter<<<NBLK, 256, 0, stream>>>(src, dstp, hist, eidx);
    // per-bucket CSR finalize: rowptr, dinv, node-sorted eidx (in-place)
    k_bucketcsr<<<BUCKETS, 256, 0, stream>>>(eidx, bstrt, rowptr, dinv);

    // Layer-1 aggregation fused with layer-2 GEMM (writes pre-scaled fp16)
    k_gathergemm<<<GEMB, 256, 0, stream>>>(bufA16, eidx, rowptr, dinv, b1, W2, bufB16);
    // Layer-2 aggregation fused with mean-pool partials
    k_gatherpool<<<GEMB, 256, 0, stream>>>(bufB16, eidx, rowptr, dinv, b2, batch, gsum);

    k_out<<<1, 128, 0, stream>>>(gsum, gcnt, Wout, bout, out);
}